// Round 5
// baseline (259.028 us; speedup 1.0000x reference)
//
#include <hip/hip_runtime.h>
#include <stdint.h>

#define N_NODES 100000
#define N_EDGES 1600000
#define FDIM 128
#define NREL 50
#define BN_EPS 1e-3f
#define N_PAD 100096
#define NBUCK 1563         // ceil(N_NODES / 64)
#define EPB 8192           // edges per ingest block
#define NBLK 196           // ceil(N_EDGES / EPB)
#define HBLK 6250          // N*32 / 512  (BN float4 blocks)
#define SCAP 1536          // bucket stride in entries (mean 1024, +16 sigma), mult of 8
#define SORTN 1792         // SCAP + 64*3 pad slack (pad-to-4 per row), mult of 4

typedef short short8_t __attribute__((ext_vector_type(8)));
typedef float f32x4_t __attribute__((ext_vector_type(4)));

__device__ __forceinline__ uint32_t f2bf(float f) {
    union { float f; uint32_t u; } v; v.f = f;
    uint32_t u = v.u;
    return (u + 0x7FFFu + ((u >> 16) & 1u)) >> 16;   // RNE, inputs finite
}
__device__ __forceinline__ float bflo(uint32_t p) {
    union { uint32_t u; float f; } v; v.u = p << 16; return v.f;
}
__device__ __forceinline__ float bfhi(uint32_t p) {
    union { uint32_t u; float f; } v; v.u = p & 0xFFFF0000u; return v.f;
}

// ---- fused prologue:
//   blocks [0,NBLK)          : edge binning into 64-row buckets with COALESCED
//                              scatter: LDS counting-sort of edge indices
//                              (perm16) -> sorted-order write so each
//                              (block,bucket) span is written contiguously.
//   block NBLK               : WT cast (bf16 transpose of dense kernel)
//   blocks (NBLK,NBLK+HBLK]  : BN h (bf16x2-packed), params L2-hot
__global__ __launch_bounds__(512) void pre_kernel(
        const float* __restrict__ x, const int* __restrict__ rows,
        const int* __restrict__ cols, const float* __restrict__ vals,
        const int* __restrict__ rels, const float* __restrict__ relc,
        const float* __restrict__ gamma, const float* __restrict__ beta,
        const float* __restrict__ mean, const float* __restrict__ var,
        const float* __restrict__ W,
        uint2* __restrict__ h, uint16_t* __restrict__ WT,
        int* __restrict__ gcur, uint2* __restrict__ staging) {
    __shared__ int lh[NBUCK];        // hist -> exclusive binstart
    __shared__ int cur[NBUCK];       // rank cursors
    __shared__ int comb[NBUCK];      // gbase - binstart
    __shared__ uint16_t perm16[EPB]; // block-local sorted order -> edge idx
    __shared__ float lrel[NREL];
    int b = blockIdx.x, t = threadIdx.x;
    if (b < NBLK) {
        if (t < NREL) lrel[t] = 1.0f / (relc[t] + 1.0f);
        for (int i = t; i < NBUCK; i += 512) lh[i] = 0;
        __syncthreads();
        int e0 = b * EPB, e1 = min(e0 + EPB, N_EDGES);
        int cntb = e1 - e0;
        // 1) histogram
        for (int e = e0 + t; e < e1; e += 512)
            atomicAdd(&lh[rows[e] >> 6], 1);
        __syncthreads();
        // 2) wave-0 exclusive scan of lh in place
        if (t < 64) {
            int carry = 0;
            for (int seg = 0; seg < (NBUCK + 63) / 64; ++seg) {
                int idx = seg * 64 + t;
                int v = (idx < NBUCK) ? lh[idx] : 0;
                int s = v;
                for (int d = 1; d < 64; d <<= 1) {
                    int u = __shfl_up(s, d);
                    if (t >= d) s += u;
                }
                if (idx < NBUCK) lh[idx] = carry + s - v;   // exclusive
                carry += __shfl(s, 63);
            }
        }
        __syncthreads();
        // 3) per-bin: reserve global span, set cursors / combined base
        for (int i = t; i < NBUCK; i += 512) {
            int bs = lh[i];
            int bn = (i + 1 < NBUCK) ? lh[i + 1] : cntb;
            int c = bn - bs;
            cur[i] = bs;
            int gb = i * SCAP + (c ? atomicAdd(&gcur[i], c) : 0);
            comb[i] = gb - bs;
        }
        __syncthreads();
        // 4) rank pass: sorted position -> local edge index
        for (int e = e0 + t; e < e1; e += 512) {
            int bk = rows[e] >> 6;                      // L2-hot reload
            int pos = atomicAdd(&cur[bk], 1);
            perm16[pos] = (uint16_t)(e - e0);
        }
        __syncthreads();
        // 5) write pass in sorted order: contiguous runs per bucket
        for (int p = t; p < cntb; p += 512) {
            int e = e0 + perm16[p];
            int r = rows[e];                            // L2-hot gather
            int bk = r >> 6;
            float w = vals[e] * lrel[rels[e]];
            int dest = comb[bk] + p;
            if (dest < (bk + 1) * SCAP) {               // statistically never false
                uint2 s;
                s.x = (uint32_t)cols[e] | ((uint32_t)(r & 63) << 20);  // col<2^17
                s.y = __float_as_uint(w);
                staging[dest] = s;
            }
        }
    } else if (b == NBLK) {
        for (int idx = t; idx < FDIM * FDIM; idx += 512) {
            int f = idx >> 7, k = idx & 127;
            WT[idx] = (uint16_t)f2bf(W[k * FDIM + f]);   // WT[f][k]
        }
    } else {
        int i4 = (b - NBLK - 1) * 512 + t;     // 0 .. N*32-1 exactly
        int cg = (i4 & 31) * 4;
        float4 xv = ((const float4*)x)[i4];
        float4 g4 = *(const float4*)(gamma + cg);
        float4 b4 = *(const float4*)(beta + cg);
        float4 m4 = *(const float4*)(mean + cg);
        float4 v4 = *(const float4*)(var + cg);
        float s0 = g4.x * rsqrtf(v4.x + BN_EPS);
        float s1 = g4.y * rsqrtf(v4.y + BN_EPS);
        float s2 = g4.z * rsqrtf(v4.z + BN_EPS);
        float s3 = g4.w * rsqrtf(v4.w + BN_EPS);
        uint2 o;
        o.x = f2bf((xv.x - m4.x) * s0 + b4.x) | (f2bf((xv.y - m4.y) * s1 + b4.y) << 16);
        o.y = f2bf((xv.z - m4.z) * s2 + b4.z) | (f2bf((xv.w - m4.w) * s3 + b4.w) << 16);
        h[i4] = o;
    }
}

// ---- fused bucket-sort + pull-SpMM + diag + GEMM (unchanged from round 4).
//   block = one 64-row bucket, 512 threads (8 waves), ~31.7KB LDS.
__global__ __launch_bounds__(512, 8) void sg_kernel(
        const uint32_t* __restrict__ h, const int* __restrict__ gcur,
        const uint2* __restrict__ staging, const float* __restrict__ ck,
        const uint16_t* __restrict__ WT, const float* __restrict__ bias,
        float* __restrict__ out) {
    __shared__ uint32_t lp[64 * 64];          // 16KB packed-bf16 tile, aliased below
    __shared__ uint2 sorted[SORTN];           // 14KB row-sorted padded edges
    __shared__ int lh[64];
    __shared__ int lcur[64];
    __shared__ uint2 rinfo[64];
    uint2* led = (uint2*)lp;                  // raw-edge buffer: SCAP=1536 <= 2048 slots

    int t = threadIdx.x;
    int wv = t >> 6, lane = t & 63;
    int b = blockIdx.x, r0 = b << 6;

    if (t < 64) lh[t] = 0;
    __syncthreads();
    int cnt = min(gcur[b], SCAP);
    const uint2* sge = staging + (size_t)b * SCAP;
    for (int e = t; e < cnt; e += 512) {
        uint2 s = sge[e];
        led[e] = s;
        atomicAdd(&lh[(s.x >> 20) & 63], 1);
    }
    __syncthreads();
    if (t < 64) {
        int v = lh[t];
        int pv = (v + 3) & ~3;               // pad each row to multiple of 4
        int s = pv;
        for (int d = 1; d < 64; d <<= 1) {
            int u = __shfl_up(s, d);
            if (t >= d) s += u;
        }
        int start = s - pv;                  // exclusive prefix
        lcur[t] = start;
        uint2 ri; ri.x = (uint32_t)start; ri.y = (uint32_t)(start + pv);
        rinfo[t] = ri;
        uint2 z; z.x = 0; z.y = 0;
        for (int k = v; k < pv; ++k) sorted[start + k] = z;   // disjoint from reorder
    }
    __syncthreads();
    for (int e = t; e < cnt; e += 512) {
        uint2 s = led[e];
        int rl = (s.x >> 20) & 63;
        int p = atomicAdd(&lcur[rl], 1);
        uint2 o; o.x = s.x & 0xFFFFFu; o.y = s.y;
        sorted[p] = o;
    }
    __syncthreads();   // led dead from here; lp writes below are safe

    // phase D: wave wv owns rows wv*8 .. +7 as 4 dual-stream pairs
#pragma unroll
    for (int i = 0; i < 4; ++i) {
        int rlA = wv * 8 + 2 * i, rlB = rlA + 1;
        int rA = r0 + rlA, rB = r0 + rlB;
        uint2 ia = rinfo[rlA], ib = rinfo[rlB];
        int eA  = __builtin_amdgcn_readfirstlane((int)ia.x);
        int e1A = __builtin_amdgcn_readfirstlane((int)ia.y);
        int eB  = __builtin_amdgcn_readfirstlane((int)ib.x);
        int e1B = __builtin_amdgcn_readfirstlane((int)ib.y);
        float axA = 0.f, ayA = 0.f, axB = 0.f, ayB = 0.f;
        if (rA < N_NODES) {
            uint32_t p = h[(uint32_t)rA * 64u + lane];
            float c = ck[rA] + 1.0f;
            axA = c * bflo(p); ayA = c * bfhi(p);
        }
        if (rB < N_NODES) {
            uint32_t p = h[(uint32_t)rB * 64u + lane];
            float c = ck[rB] + 1.0f;
            axB = c * bflo(p); ayB = c * bfhi(p);
        }
        while (eA < e1A && eB < e1B) {
            uint4 a0 = *(const uint4*)&sorted[eA];       // broadcast LDS reads
            uint4 a1 = *(const uint4*)&sorted[eA + 2];
            uint4 b0 = *(const uint4*)&sorted[eB];
            uint4 b1 = *(const uint4*)&sorted[eB + 2];
            uint32_t qa0 = h[a0.x * 64u + lane];
            uint32_t qa1 = h[a0.z * 64u + lane];
            uint32_t qa2 = h[a1.x * 64u + lane];
            uint32_t qa3 = h[a1.z * 64u + lane];
            uint32_t qb0 = h[b0.x * 64u + lane];
            uint32_t qb1 = h[b0.z * 64u + lane];
            uint32_t qb2 = h[b1.x * 64u + lane];
            uint32_t qb3 = h[b1.z * 64u + lane];
            float wa0 = __uint_as_float(a0.y), wa1 = __uint_as_float(a0.w);
            float wa2 = __uint_as_float(a1.y), wa3 = __uint_as_float(a1.w);
            float wb0 = __uint_as_float(b0.y), wb1 = __uint_as_float(b0.w);
            float wb2 = __uint_as_float(b1.y), wb3 = __uint_as_float(b1.w);
            axA += wa0 * bflo(qa0); ayA += wa0 * bfhi(qa0);
            axA += wa1 * bflo(qa1); ayA += wa1 * bfhi(qa1);
            axA += wa2 * bflo(qa2); ayA += wa2 * bfhi(qa2);
            axA += wa3 * bflo(qa3); ayA += wa3 * bfhi(qa3);
            axB += wb0 * bflo(qb0); ayB += wb0 * bfhi(qb0);
            axB += wb1 * bflo(qb1); ayB += wb1 * bfhi(qb1);
            axB += wb2 * bflo(qb2); ayB += wb2 * bfhi(qb2);
            axB += wb3 * bflo(qb3); ayB += wb3 * bfhi(qb3);
            eA += 4; eB += 4;
        }
        while (eA < e1A) {
            uint4 a0 = *(const uint4*)&sorted[eA];
            uint4 a1 = *(const uint4*)&sorted[eA + 2];
            uint32_t qa0 = h[a0.x * 64u + lane];
            uint32_t qa1 = h[a0.z * 64u + lane];
            uint32_t qa2 = h[a1.x * 64u + lane];
            uint32_t qa3 = h[a1.z * 64u + lane];
            float wa0 = __uint_as_float(a0.y), wa1 = __uint_as_float(a0.w);
            float wa2 = __uint_as_float(a1.y), wa3 = __uint_as_float(a1.w);
            axA += wa0 * bflo(qa0); ayA += wa0 * bfhi(qa0);
            axA += wa1 * bflo(qa1); ayA += wa1 * bfhi(qa1);
            axA += wa2 * bflo(qa2); ayA += wa2 * bfhi(qa2);
            axA += wa3 * bflo(qa3); ayA += wa3 * bfhi(qa3);
            eA += 4;
        }
        while (eB < e1B) {
            uint4 b0 = *(const uint4*)&sorted[eB];
            uint4 b1 = *(const uint4*)&sorted[eB + 2];
            uint32_t qb0 = h[b0.x * 64u + lane];
            uint32_t qb1 = h[b0.z * 64u + lane];
            uint32_t qb2 = h[b1.x * 64u + lane];
            uint32_t qb3 = h[b1.z * 64u + lane];
            float wb0 = __uint_as_float(b0.y), wb1 = __uint_as_float(b0.w);
            float wb2 = __uint_as_float(b1.y), wb3 = __uint_as_float(b1.w);
            axB += wb0 * bflo(qb0); ayB += wb0 * bfhi(qb0);
            axB += wb1 * bflo(qb1); ayB += wb1 * bfhi(qb1);
            axB += wb2 * bflo(qb2); ayB += wb2 * bfhi(qb2);
            axB += wb3 * bflo(qb3); ayB += wb3 * bfhi(qb3);
            eB += 4;
        }
        lp[rlA * 64 + (lane ^ ((rlA & 7) << 2))] = f2bf(axA) | (f2bf(ayA) << 16);
        lp[rlB * 64 + (lane ^ ((rlB & 7) << 2))] = f2bf(axB) | (f2bf(ayB) << 16);
    }
    __syncthreads();

    // phase E: wave wv -> rows (wv&3)*16..+15, cols (wv>>2)*64..+63
    int m = lane & 15, q = lane >> 4;
    int rl0 = (wv & 3) << 4;
    int colb = (wv >> 2) << 6;
    int rlm = rl0 + m;
    short8_t a[4];
#pragma unroll
    for (int tt = 0; tt < 4; ++tt) {
        int w0 = (q * 4 + tt * 16) ^ ((rlm & 7) << 2);
        a[tt] = *(const short8_t*)&lp[rlm * 64 + w0];
    }
#pragma unroll
    for (int ct = 0; ct < 4; ++ct) {
        int col0 = colb + ct * 16;
        const uint16_t* brow = WT + (size_t)(col0 + m) * FDIM + q * 8;
        f32x4_t acc = {0.f, 0.f, 0.f, 0.f};
#pragma unroll
        for (int tt = 0; tt < 4; ++tt) {
            short8_t bb = *(const short8_t*)(brow + tt * 32);
            acc = __builtin_amdgcn_mfma_f32_16x16x32_bf16(a[tt], bb, acc, 0, 0, 0);
        }
        float bs = bias[col0 + m];
#pragma unroll
        for (int r = 0; r < 4; ++r) {
            int row = r0 + rl0 + q * 4 + r;
            if (row < N_NODES)
                out[(size_t)row * FDIM + col0 + m] = acc[r] + bs;
        }
    }
}

extern "C" void kernel_launch(void* const* d_in, const int* in_sizes, int n_in,
                              void* d_out, int out_size, void* d_ws, size_t ws_size,
                              hipStream_t stream) {
    const float* x     = (const float*)d_in[0];
    const int*   erows = (const int*)d_in[1];
    const int*   ecols = (const int*)d_in[2];
    const float* evals = (const float*)d_in[3];
    const int*   erels = (const int*)d_in[4];
    const float* relc  = (const float*)d_in[5];
    const float* ck    = (const float*)d_in[6];
    const float* W     = (const float*)d_in[7];
    const float* bias  = (const float*)d_in[8];
    const float* gamma = (const float*)d_in[9];
    const float* beta  = (const float*)d_in[10];
    const float* mean  = (const float*)d_in[11];
    const float* var   = (const float*)d_in[12];
    float* out = (float*)d_out;

    char* wp = (char*)d_ws;
    auto alloc = [&](size_t bytes) {
        char* p = wp;
        wp += (bytes + 255) & ~(size_t)255;
        return (void*)p;
    };
    uint16_t* h      = (uint16_t*)alloc((size_t)N_PAD * FDIM * 2);       // 25.6 MB
    uint2* staging   = (uint2*)alloc((size_t)NBUCK * SCAP * 8);          // 19.2 MB
    int* gcur        = (int*)alloc((size_t)NBUCK * 4);
    uint16_t* WT     = (uint16_t*)alloc(FDIM * FDIM * 2);
    if ((size_t)(wp - (char*)d_ws) > ws_size) return;

    hipMemsetAsync(gcur, 0, (size_t)NBUCK * 4, stream);
    pre_kernel<<<NBLK + 1 + HBLK, 512, 0, stream>>>(
        x, erows, ecols, evals, erels, relc, gamma, beta, mean, var, W,
        (uint2*)h, WT, gcur, staging);
    sg_kernel<<<NBUCK, 512, 0, stream>>>((const uint32_t*)h, gcur, staging, ck,
                                         WT, bias, out);
}

// Round 6
// 255.053 us; speedup vs baseline: 1.0156x; 1.0156x over previous
//
#include <hip/hip_runtime.h>
#include <stdint.h>

#define N_NODES 100000
#define N_EDGES 1600000
#define FDIM 128
#define NREL 50
#define BN_EPS 1e-3f
#define N_PAD 100096
#define NBUCK 1563         // ceil(N_NODES / 64)
#define EPB 8192           // edges per ingest block
#define NBLK 196           // ceil(N_EDGES / EPB)
#define HBLK 6250          // N*32 / 512  (BN float4 blocks)
#define SCAP 1536          // bucket stride in entries (mean 1024, +16 sigma), mult of 8
#define SORTN 1984         // SCAP + 64*7 pad slack (pad-to-8 per row), mult of 8

typedef short short8_t __attribute__((ext_vector_type(8)));
typedef float f32x4_t __attribute__((ext_vector_type(4)));

__device__ __forceinline__ uint32_t f2bf(float f) {
    union { float f; uint32_t u; } v; v.f = f;
    uint32_t u = v.u;
    return (u + 0x7FFFu + ((u >> 16) & 1u)) >> 16;   // RNE, inputs finite
}
__device__ __forceinline__ float bflo(uint32_t p) {
    union { uint32_t u; float f; } v; v.u = p << 16; return v.f;
}
__device__ __forceinline__ float bfhi(uint32_t p) {
    union { uint32_t u; float f; } v; v.u = p & 0xFFFF0000u; return v.f;
}

// ---- fused prologue (round-4 simple-scatter version):
//   blocks [0,NBLK)          : edge binning into 64-row buckets (LDS hist ->
//                              one global atomicAdd per bucket -> scatter)
//   block NBLK               : WT cast (bf16 transpose of dense kernel)
//   blocks (NBLK,NBLK+HBLK]  : BN h (bf16x2-packed), params L2-hot
__global__ __launch_bounds__(512) void pre_kernel(
        const float* __restrict__ x, const int* __restrict__ rows,
        const int* __restrict__ cols, const float* __restrict__ vals,
        const int* __restrict__ rels, const float* __restrict__ relc,
        const float* __restrict__ gamma, const float* __restrict__ beta,
        const float* __restrict__ mean, const float* __restrict__ var,
        const float* __restrict__ W,
        uint2* __restrict__ h, uint16_t* __restrict__ WT,
        int* __restrict__ gcur, uint2* __restrict__ staging) {
    __shared__ int lh[NBUCK];
    __shared__ float lrel[NREL];
    int b = blockIdx.x, t = threadIdx.x;
    if (b < NBLK) {
        if (t < NREL) lrel[t] = 1.0f / (relc[t] + 1.0f);
        for (int i = t; i < NBUCK; i += 512) lh[i] = 0;
        __syncthreads();
        int e0 = b * EPB, e1 = min(e0 + EPB, N_EDGES);
        for (int e = e0 + t; e < e1; e += 512)
            atomicAdd(&lh[rows[e] >> 6], 1);
        __syncthreads();
        for (int i = t; i < NBUCK; i += 512) {
            int c = lh[i];
            int base = c ? atomicAdd(&gcur[i], c) : 0;
            lh[i] = i * SCAP + base;           // absolute cursor into staging
        }
        __syncthreads();
        for (int e = e0 + t; e < e1; e += 512) {
            int r = rows[e];
            int bk = r >> 6;
            float w = vals[e] * lrel[rels[e]];
            int p = atomicAdd(&lh[bk], 1);
            if (p < (bk + 1) * SCAP) {          // statistically never taken
                uint2 s;
                s.x = (uint32_t)cols[e] | ((uint32_t)(r & 63) << 20);  // col<2^17
                s.y = __float_as_uint(w);
                staging[p] = s;
            }
        }
    } else if (b == NBLK) {
        for (int idx = t; idx < FDIM * FDIM; idx += 512) {
            int f = idx >> 7, k = idx & 127;
            WT[idx] = (uint16_t)f2bf(W[k * FDIM + f]);   // WT[f][k]
        }
    } else {
        int i4 = (b - NBLK - 1) * 512 + t;     // 0 .. N*32-1 exactly
        int cg = (i4 & 31) * 4;
        float4 xv = ((const float4*)x)[i4];
        float4 g4 = *(const float4*)(gamma + cg);
        float4 b4 = *(const float4*)(beta + cg);
        float4 m4 = *(const float4*)(mean + cg);
        float4 v4 = *(const float4*)(var + cg);
        float s0 = g4.x * rsqrtf(v4.x + BN_EPS);
        float s1 = g4.y * rsqrtf(v4.y + BN_EPS);
        float s2 = g4.z * rsqrtf(v4.z + BN_EPS);
        float s3 = g4.w * rsqrtf(v4.w + BN_EPS);
        uint2 o;
        o.x = f2bf((xv.x - m4.x) * s0 + b4.x) | (f2bf((xv.y - m4.y) * s1 + b4.y) << 16);
        o.y = f2bf((xv.z - m4.z) * s2 + b4.z) | (f2bf((xv.w - m4.w) * s3 + b4.w) << 16);
        h[i4] = o;
    }
}

// 2-edges-per-instruction gather step for one stream:
//   dK = sorted[e + 2k + hsel] : lower half gets edge 2k, upper edge 2k+1.
#define GSTEP(d, q, s0, s1, s2, s3) {                 \
    float w_ = __uint_as_float((d).y);                \
    s0 += w_ * bflo((q).x); s1 += w_ * bfhi((q).x);   \
    s2 += w_ * bflo((q).y); s3 += w_ * bfhi((q).y); }

// ---- fused bucket-sort + pull-SpMM + diag + GEMM.
//   block = one 64-row bucket, 512 threads (8 waves), ~32.7KB LDS
//   -> 4 blocks/CU.
//   Phase A: coalesced load of bucket edges into LDS + 64-bin row histogram.
//   Phase B: wave64 shfl prefix scan (pad-to-8) -> per-row ranges + zero pads.
//   Phase C: LDS reorder into row-sorted buffer.
//   Phase D: HALF-WAVE pull loop -- h rows read as 32 lanes x 8B, so one
//            global_load_dwordx2 covers TWO edges (lower/upper half of the
//            wave process edges e / e+1). Dual row streams keep 8 loads
//            (16 edges) in flight. Cross-half combine via shfl_xor(32).
//   Phase E: 64x128 MFMA tile + bias -> out. ----
__global__ __launch_bounds__(512, 8) void sg_kernel(
        const uint32_t* __restrict__ hw, const int* __restrict__ gcur,
        const uint2* __restrict__ staging, const float* __restrict__ ck,
        const uint16_t* __restrict__ WT, const float* __restrict__ bias,
        float* __restrict__ out) {
    __shared__ uint32_t lp[64 * 64];          // 16KB packed-bf16 tile, aliased below
    __shared__ uint2 sorted[SORTN];           // 15.9KB row-sorted padded edges
    __shared__ int lh[64];
    __shared__ int lcur[64];
    __shared__ uint2 rinfo[64];
    uint2* led = (uint2*)lp;                  // raw-edge buffer: SCAP=1536 <= 2048 slots
    const uint2* h2 = (const uint2*)hw;       // h rows: 32 x uint2 (8B/lane)

    int t = threadIdx.x;
    int wv = t >> 6, lane = t & 63;
    int hl = lane & 31, hsel = lane >> 5;
    int b = blockIdx.x, r0 = b << 6;

    if (t < 64) lh[t] = 0;
    __syncthreads();
    int cnt = min(gcur[b], SCAP);
    const uint2* sge = staging + (size_t)b * SCAP;
    for (int e = t; e < cnt; e += 512) {
        uint2 s = sge[e];
        led[e] = s;
        atomicAdd(&lh[(s.x >> 20) & 63], 1);
    }
    __syncthreads();
    if (t < 64) {
        int v = lh[t];
        int pv = (v + 7) & ~7;               // pad each row to multiple of 8
        int s = pv;
        for (int d = 1; d < 64; d <<= 1) {
            int u = __shfl_up(s, d);
            if (t >= d) s += u;
        }
        int start = s - pv;                  // exclusive prefix
        lcur[t] = start;
        uint2 ri; ri.x = (uint32_t)start; ri.y = (uint32_t)(start + pv);
        rinfo[t] = ri;
        uint2 z; z.x = 0; z.y = 0;           // pad: col 0, weight 0 (h row 0, L1-hot)
        for (int k = v; k < pv; ++k) sorted[start + k] = z;   // disjoint from reorder
    }
    __syncthreads();
    for (int e = t; e < cnt; e += 512) {
        uint2 s = led[e];
        int rl = (s.x >> 20) & 63;
        int p = atomicAdd(&lcur[rl], 1);
        uint2 o; o.x = s.x & 0xFFFFFu; o.y = s.y;
        sorted[p] = o;
    }
    __syncthreads();   // led dead from here; lp writes below are safe

    // phase D: wave wv owns rows wv*8 .. +7 as 4 dual-row streams
#pragma unroll
    for (int i = 0; i < 4; ++i) {
        int rlA = wv * 8 + 2 * i, rlB = rlA + 1;
        int rA = r0 + rlA, rB = r0 + rlB;
        uint2 ia = rinfo[rlA], ib = rinfo[rlB];
        int eA  = __builtin_amdgcn_readfirstlane((int)ia.x);
        int e1A = __builtin_amdgcn_readfirstlane((int)ia.y);
        int eB  = __builtin_amdgcn_readfirstlane((int)ib.x);
        int e1B = __builtin_amdgcn_readfirstlane((int)ib.y);
        // diag init: lower half seeds stream A, upper half seeds stream B
        int rsel = hsel ? rB : rA;
        int rc = min(rsel, N_NODES - 1);
        uint2 p = h2[(uint32_t)rc * 32u + hl];
        float cv = ck[rc] + 1.0f;
        cv = (rsel < N_NODES) ? cv : 0.0f;
        float f0 = cv * bflo(p.x), f1 = cv * bfhi(p.x);
        float f2 = cv * bflo(p.y), f3 = cv * bfhi(p.y);
        float a0 = hsel ? 0.f : f0, a1 = hsel ? 0.f : f1;
        float a2 = hsel ? 0.f : f2, a3 = hsel ? 0.f : f3;
        float b0 = hsel ? f0 : 0.f, b1 = hsel ? f1 : 0.f;
        float b2 = hsel ? f2 : 0.f, b3 = hsel ? f3 : 0.f;

        while (eA < e1A && eB < e1B) {       // 16 edges, 8 dwordx2 gathers in flight
            uint2 dA0 = sorted[eA + 0 + hsel];
            uint2 dA1 = sorted[eA + 2 + hsel];
            uint2 dA2 = sorted[eA + 4 + hsel];
            uint2 dA3 = sorted[eA + 6 + hsel];
            uint2 dB0 = sorted[eB + 0 + hsel];
            uint2 dB1 = sorted[eB + 2 + hsel];
            uint2 dB2 = sorted[eB + 4 + hsel];
            uint2 dB3 = sorted[eB + 6 + hsel];
            uint2 qA0 = h2[dA0.x * 32u + hl];
            uint2 qA1 = h2[dA1.x * 32u + hl];
            uint2 qA2 = h2[dA2.x * 32u + hl];
            uint2 qA3 = h2[dA3.x * 32u + hl];
            uint2 qB0 = h2[dB0.x * 32u + hl];
            uint2 qB1 = h2[dB1.x * 32u + hl];
            uint2 qB2 = h2[dB2.x * 32u + hl];
            uint2 qB3 = h2[dB3.x * 32u + hl];
            GSTEP(dA0, qA0, a0, a1, a2, a3); GSTEP(dA1, qA1, a0, a1, a2, a3);
            GSTEP(dA2, qA2, a0, a1, a2, a3); GSTEP(dA3, qA3, a0, a1, a2, a3);
            GSTEP(dB0, qB0, b0, b1, b2, b3); GSTEP(dB1, qB1, b0, b1, b2, b3);
            GSTEP(dB2, qB2, b0, b1, b2, b3); GSTEP(dB3, qB3, b0, b1, b2, b3);
            eA += 8; eB += 8;
        }
        while (eA < e1A) {
            uint2 dA0 = sorted[eA + 0 + hsel];
            uint2 dA1 = sorted[eA + 2 + hsel];
            uint2 dA2 = sorted[eA + 4 + hsel];
            uint2 dA3 = sorted[eA + 6 + hsel];
            uint2 qA0 = h2[dA0.x * 32u + hl];
            uint2 qA1 = h2[dA1.x * 32u + hl];
            uint2 qA2 = h2[dA2.x * 32u + hl];
            uint2 qA3 = h2[dA3.x * 32u + hl];
            GSTEP(dA0, qA0, a0, a1, a2, a3); GSTEP(dA1, qA1, a0, a1, a2, a3);
            GSTEP(dA2, qA2, a0, a1, a2, a3); GSTEP(dA3, qA3, a0, a1, a2, a3);
            eA += 8;
        }
        while (eB < e1B) {
            uint2 dB0 = sorted[eB + 0 + hsel];
            uint2 dB1 = sorted[eB + 2 + hsel];
            uint2 dB2 = sorted[eB + 4 + hsel];
            uint2 dB3 = sorted[eB + 6 + hsel];
            uint2 qB0 = h2[dB0.x * 32u + hl];
            uint2 qB1 = h2[dB1.x * 32u + hl];
            uint2 qB2 = h2[dB2.x * 32u + hl];
            uint2 qB3 = h2[dB3.x * 32u + hl];
            GSTEP(dB0, qB0, b0, b1, b2, b3); GSTEP(dB1, qB1, b0, b1, b2, b3);
            GSTEP(dB2, qB2, b0, b1, b2, b3); GSTEP(dB3, qB3, b0, b1, b2, b3);
            eB += 8;
        }
        // fold the two halves: each feature group summed across lane^32
        a0 += __shfl_xor(a0, 32, 64); a1 += __shfl_xor(a1, 32, 64);
        a2 += __shfl_xor(a2, 32, 64); a3 += __shfl_xor(a3, 32, 64);
        b0 += __shfl_xor(b0, 32, 64); b1 += __shfl_xor(b1, 32, 64);
        b2 += __shfl_xor(b2, 32, 64); b3 += __shfl_xor(b3, 32, 64);
        if (lane < 32) {
            int cA = (rlA & 7) << 2, cB = (rlB & 7) << 2;
            uint2 wA, wB;
            wA.x = f2bf(a0) | (f2bf(a1) << 16); wA.y = f2bf(a2) | (f2bf(a3) << 16);
            wB.x = f2bf(b0) | (f2bf(b1) << 16); wB.y = f2bf(b2) | (f2bf(b3) << 16);
            *(uint2*)&lp[rlA * 64 + ((2 * hl) ^ cA)] = wA;   // (2hl)^c even -> 8B aligned
            *(uint2*)&lp[rlB * 64 + ((2 * hl) ^ cB)] = wB;
        }
    }
    __syncthreads();

    // phase E: wave wv -> rows (wv&3)*16..+15, cols (wv>>2)*64..+63
    int m = lane & 15, q = lane >> 4;
    int rl0 = (wv & 3) << 4;
    int colb = (wv >> 2) << 6;
    int rlm = rl0 + m;
    short8_t a[4];
#pragma unroll
    for (int tt = 0; tt < 4; ++tt) {
        int w0 = (q * 4 + tt * 16) ^ ((rlm & 7) << 2);
        a[tt] = *(const short8_t*)&lp[rlm * 64 + w0];
    }
#pragma unroll
    for (int ct = 0; ct < 4; ++ct) {
        int col0 = colb + ct * 16;
        const uint16_t* brow = WT + (size_t)(col0 + m) * FDIM + q * 8;
        f32x4_t acc = {0.f, 0.f, 0.f, 0.f};
#pragma unroll
        for (int tt = 0; tt < 4; ++tt) {
            short8_t bb = *(const short8_t*)(brow + tt * 32);
            acc = __builtin_amdgcn_mfma_f32_16x16x32_bf16(a[tt], bb, acc, 0, 0, 0);
        }
        float bs = bias[col0 + m];
#pragma unroll
        for (int r = 0; r < 4; ++r) {
            int row = r0 + rl0 + q * 4 + r;
            if (row < N_NODES)
                out[(size_t)row * FDIM + col0 + m] = acc[r] + bs;
        }
    }
}

extern "C" void kernel_launch(void* const* d_in, const int* in_sizes, int n_in,
                              void* d_out, int out_size, void* d_ws, size_t ws_size,
                              hipStream_t stream) {
    const float* x     = (const float*)d_in[0];
    const int*   erows = (const int*)d_in[1];
    const int*   ecols = (const int*)d_in[2];
    const float* evals = (const float*)d_in[3];
    const int*   erels = (const int*)d_in[4];
    const float* relc  = (const float*)d_in[5];
    const float* ck    = (const float*)d_in[6];
    const float* W     = (const float*)d_in[7];
    const float* bias  = (const float*)d_in[8];
    const float* gamma = (const float*)d_in[9];
    const float* beta  = (const float*)d_in[10];
    const float* mean  = (const float*)d_in[11];
    const float* var   = (const float*)d_in[12];
    float* out = (float*)d_out;

    char* wp = (char*)d_ws;
    auto alloc = [&](size_t bytes) {
        char* p = wp;
        wp += (bytes + 255) & ~(size_t)255;
        return (void*)p;
    };
    uint16_t* h      = (uint16_t*)alloc((size_t)N_PAD * FDIM * 2);       // 25.6 MB
    uint2* staging   = (uint2*)alloc((size_t)NBUCK * SCAP * 8);          // 19.2 MB
    int* gcur        = (int*)alloc((size_t)NBUCK * 4);
    uint16_t* WT     = (uint16_t*)alloc(FDIM * FDIM * 2);
    if ((size_t)(wp - (char*)d_ws) > ws_size) return;

    hipMemsetAsync(gcur, 0, (size_t)NBUCK * 4, stream);
    pre_kernel<<<NBLK + 1 + HBLK, 512, 0, stream>>>(
        x, erows, ecols, evals, erels, relc, gamma, beta, mean, var, W,
        (uint2*)h, WT, gcur, staging);
    sg_kernel<<<NBUCK, 512, 0, stream>>>((const uint32_t*)h, gcur, staging, ck,
                                         WT, bias, out);
}

// Round 7
// 254.836 us; speedup vs baseline: 1.0164x; 1.0009x over previous
//
#include <hip/hip_runtime.h>
#include <stdint.h>

#define N_NODES 100000
#define N_EDGES 1600000
#define FDIM 128
#define NREL 50
#define BN_EPS 1e-3f
#define N_PAD 100096
#define NBUCK 3125         // N_NODES / 32 exactly
#define EPB 8192           // edges per ingest block
#define NBLK 196           // ceil(N_EDGES / EPB)
#define HBLK 6250          // N*32 / 512  (BN float4 blocks)
#define SCAP 768           // bucket stride in entries (mean 512, +11 sigma), mult of 8
#define SORTN 992          // SCAP + 32*7 pad slack (pad-to-8 per row), mult of 8

typedef short short8_t __attribute__((ext_vector_type(8)));
typedef float f32x4_t __attribute__((ext_vector_type(4)));

__device__ __forceinline__ uint32_t f2bf(float f) {
    union { float f; uint32_t u; } v; v.f = f;
    uint32_t u = v.u;
    return (u + 0x7FFFu + ((u >> 16) & 1u)) >> 16;   // RNE, inputs finite
}
__device__ __forceinline__ float bflo(uint32_t p) {
    union { uint32_t u; float f; } v; v.u = p << 16; return v.f;
}
__device__ __forceinline__ float bfhi(uint32_t p) {
    union { uint32_t u; float f; } v; v.u = p & 0xFFFF0000u; return v.f;
}

// ---- fused prologue:
//   blocks [0,NBLK)          : edge binning into 32-row buckets (LDS hist ->
//                              one global atomicAdd per bucket -> scatter)
//   block NBLK               : WT cast (bf16 transpose of dense kernel)
//   blocks (NBLK,NBLK+HBLK]  : BN h (bf16x2-packed), params L2-hot
__global__ __launch_bounds__(512) void pre_kernel(
        const float* __restrict__ x, const int* __restrict__ rows,
        const int* __restrict__ cols, const float* __restrict__ vals,
        const int* __restrict__ rels, const float* __restrict__ relc,
        const float* __restrict__ gamma, const float* __restrict__ beta,
        const float* __restrict__ mean, const float* __restrict__ var,
        const float* __restrict__ W,
        uint2* __restrict__ h, uint16_t* __restrict__ WT,
        int* __restrict__ gcur, uint2* __restrict__ staging) {
    __shared__ int lh[NBUCK];                 // 12.5 KB
    __shared__ float lrel[NREL];
    int b = blockIdx.x, t = threadIdx.x;
    if (b < NBLK) {
        if (t < NREL) lrel[t] = 1.0f / (relc[t] + 1.0f);
        for (int i = t; i < NBUCK; i += 512) lh[i] = 0;
        __syncthreads();
        int e0 = b * EPB, e1 = min(e0 + EPB, N_EDGES);
        for (int e = e0 + t; e < e1; e += 512)
            atomicAdd(&lh[rows[e] >> 5], 1);
        __syncthreads();
        for (int i = t; i < NBUCK; i += 512) {
            int c = lh[i];
            int base = c ? atomicAdd(&gcur[i], c) : 0;
            lh[i] = i * SCAP + base;           // absolute cursor into staging
        }
        __syncthreads();
        for (int e = e0 + t; e < e1; e += 512) {
            int r = rows[e];
            int bk = r >> 5;
            float w = vals[e] * lrel[rels[e]];
            int p = atomicAdd(&lh[bk], 1);
            if (p < (bk + 1) * SCAP) {          // statistically never taken
                uint2 s;
                s.x = (uint32_t)cols[e] | ((uint32_t)(r & 31) << 20);  // col<2^17
                s.y = __float_as_uint(w);
                staging[p] = s;
            }
        }
    } else if (b == NBLK) {
        for (int idx = t; idx < FDIM * FDIM; idx += 512) {
            int f = idx >> 7, k = idx & 127;
            WT[idx] = (uint16_t)f2bf(W[k * FDIM + f]);   // WT[f][k]
        }
    } else {
        int i4 = (b - NBLK - 1) * 512 + t;     // 0 .. N*32-1 exactly
        int cg = (i4 & 31) * 4;
        float4 xv = ((const float4*)x)[i4];
        float4 g4 = *(const float4*)(gamma + cg);
        float4 b4 = *(const float4*)(beta + cg);
        float4 m4 = *(const float4*)(mean + cg);
        float4 v4 = *(const float4*)(var + cg);
        float s0 = g4.x * rsqrtf(v4.x + BN_EPS);
        float s1 = g4.y * rsqrtf(v4.y + BN_EPS);
        float s2 = g4.z * rsqrtf(v4.z + BN_EPS);
        float s3 = g4.w * rsqrtf(v4.w + BN_EPS);
        uint2 o;
        o.x = f2bf((xv.x - m4.x) * s0 + b4.x) | (f2bf((xv.y - m4.y) * s1 + b4.y) << 16);
        o.y = f2bf((xv.z - m4.z) * s2 + b4.z) | (f2bf((xv.w - m4.w) * s3 + b4.w) << 16);
        h[i4] = o;
    }
}

// 2-edges-per-instruction gather step for one stream:
#define GSTEP(d, q, s0, s1, s2, s3) {                 \
    float w_ = __uint_as_float((d).y);                \
    s0 += w_ * bflo((q).x); s1 += w_ * bfhi((q).x);   \
    s2 += w_ * bflo((q).y); s3 += w_ * bfhi((q).y); }

// ---- fused bucket-sort + pull-SpMM + diag + GEMM.
//   block = one 32-row bucket, 256 threads (4 waves), ~16.6KB LDS
//   -> 8 blocks/CU (wave cap 32): halves tail waste + barrier granularity
//   vs the 64-row version. 3125*32 == N exactly -> no bounds checks.
//   Phase A: coalesced load of bucket edges into LDS + 32-bin row histogram.
//   Phase B: 32-lane shfl prefix scan (pad-to-8) -> per-row ranges + zero pads.
//   Phase C: LDS reorder into row-sorted buffer.
//   Phase D: half-wave pull loop (h rows as 32 lanes x 8B; one dwordx2 covers
//            TWO edges), dual row streams, 8 loads (16 edges) in flight,
//            cross-half combine via shfl_xor(32).
//   Phase E: 32x128 MFMA tile + bias -> out. ----
__global__ __launch_bounds__(256, 8) void sg_kernel(
        const uint32_t* __restrict__ hw, const int* __restrict__ gcur,
        const uint2* __restrict__ staging, const float* __restrict__ ck,
        const uint16_t* __restrict__ WT, const float* __restrict__ bias,
        float* __restrict__ out) {
    __shared__ uint32_t lp[32 * 64];          // 8KB packed-bf16 tile, aliased below
    __shared__ uint2 sorted[SORTN];           // 7.75KB row-sorted padded edges
    __shared__ int lh[32];
    __shared__ int lcur[32];
    __shared__ uint2 rinfo[32];
    uint2* led = (uint2*)lp;                  // raw-edge buffer: SCAP=768 <= 1024 slots
    const uint2* h2 = (const uint2*)hw;       // h rows: 32 x uint2 (8B/lane)

    int t = threadIdx.x;
    int wv = t >> 6, lane = t & 63;
    int hl = lane & 31, hsel = lane >> 5;
    int b = blockIdx.x, r0 = b << 5;

    if (t < 32) lh[t] = 0;
    __syncthreads();
    int cnt = min(gcur[b], SCAP);
    const uint2* sge = staging + (size_t)b * SCAP;
    for (int e = t; e < cnt; e += 256) {
        uint2 s = sge[e];
        led[e] = s;
        atomicAdd(&lh[(s.x >> 20) & 31], 1);
    }
    __syncthreads();
    if (t < 32) {
        int v = lh[t];
        int pv = (v + 7) & ~7;               // pad each row to multiple of 8
        int s = pv;
        for (int d = 1; d < 32; d <<= 1) {
            int u = __shfl_up(s, d);
            if (t >= d) s += u;
        }
        int start = s - pv;                  // exclusive prefix
        lcur[t] = start;
        uint2 ri; ri.x = (uint32_t)start; ri.y = (uint32_t)(start + pv);
        rinfo[t] = ri;
        uint2 z; z.x = 0; z.y = 0;           // pad: col 0, weight 0 (h row 0, L1-hot)
        for (int k = v; k < pv; ++k) sorted[start + k] = z;   // disjoint from reorder
    }
    __syncthreads();
    for (int e = t; e < cnt; e += 256) {
        uint2 s = led[e];
        int rl = (s.x >> 20) & 31;
        int p = atomicAdd(&lcur[rl], 1);
        uint2 o; o.x = s.x & 0xFFFFFu; o.y = s.y;
        sorted[p] = o;
    }
    __syncthreads();   // led dead from here; lp writes below are safe

    // phase D: wave wv owns rows wv*8 .. +7 as 4 dual-row streams
#pragma unroll
    for (int i = 0; i < 4; ++i) {
        int rlA = wv * 8 + 2 * i, rlB = rlA + 1;
        int rA = r0 + rlA, rB = r0 + rlB;
        uint2 ia = rinfo[rlA], ib = rinfo[rlB];
        int eA  = __builtin_amdgcn_readfirstlane((int)ia.x);
        int e1A = __builtin_amdgcn_readfirstlane((int)ia.y);
        int eB  = __builtin_amdgcn_readfirstlane((int)ib.x);
        int e1B = __builtin_amdgcn_readfirstlane((int)ib.y);
        // diag init: lower half seeds stream A, upper half seeds stream B
        int rsel = hsel ? rB : rA;
        uint2 p = h2[(uint32_t)rsel * 32u + hl];
        float cv = ck[rsel] + 1.0f;
        float f0 = cv * bflo(p.x), f1 = cv * bfhi(p.x);
        float f2 = cv * bflo(p.y), f3 = cv * bfhi(p.y);
        float a0 = hsel ? 0.f : f0, a1 = hsel ? 0.f : f1;
        float a2 = hsel ? 0.f : f2, a3 = hsel ? 0.f : f3;
        float b0 = hsel ? f0 : 0.f, b1 = hsel ? f1 : 0.f;
        float b2 = hsel ? f2 : 0.f, b3 = hsel ? f3 : 0.f;

        while (eA < e1A && eB < e1B) {       // 16 edges, 8 dwordx2 gathers in flight
            uint2 dA0 = sorted[eA + 0 + hsel];
            uint2 dA1 = sorted[eA + 2 + hsel];
            uint2 dA2 = sorted[eA + 4 + hsel];
            uint2 dA3 = sorted[eA + 6 + hsel];
            uint2 dB0 = sorted[eB + 0 + hsel];
            uint2 dB1 = sorted[eB + 2 + hsel];
            uint2 dB2 = sorted[eB + 4 + hsel];
            uint2 dB3 = sorted[eB + 6 + hsel];
            uint2 qA0 = h2[dA0.x * 32u + hl];
            uint2 qA1 = h2[dA1.x * 32u + hl];
            uint2 qA2 = h2[dA2.x * 32u + hl];
            uint2 qA3 = h2[dA3.x * 32u + hl];
            uint2 qB0 = h2[dB0.x * 32u + hl];
            uint2 qB1 = h2[dB1.x * 32u + hl];
            uint2 qB2 = h2[dB2.x * 32u + hl];
            uint2 qB3 = h2[dB3.x * 32u + hl];
            GSTEP(dA0, qA0, a0, a1, a2, a3); GSTEP(dA1, qA1, a0, a1, a2, a3);
            GSTEP(dA2, qA2, a0, a1, a2, a3); GSTEP(dA3, qA3, a0, a1, a2, a3);
            GSTEP(dB0, qB0, b0, b1, b2, b3); GSTEP(dB1, qB1, b0, b1, b2, b3);
            GSTEP(dB2, qB2, b0, b1, b2, b3); GSTEP(dB3, qB3, b0, b1, b2, b3);
            eA += 8; eB += 8;
        }
        while (eA < e1A) {
            uint2 dA0 = sorted[eA + 0 + hsel];
            uint2 dA1 = sorted[eA + 2 + hsel];
            uint2 dA2 = sorted[eA + 4 + hsel];
            uint2 dA3 = sorted[eA + 6 + hsel];
            uint2 qA0 = h2[dA0.x * 32u + hl];
            uint2 qA1 = h2[dA1.x * 32u + hl];
            uint2 qA2 = h2[dA2.x * 32u + hl];
            uint2 qA3 = h2[dA3.x * 32u + hl];
            GSTEP(dA0, qA0, a0, a1, a2, a3); GSTEP(dA1, qA1, a0, a1, a2, a3);
            GSTEP(dA2, qA2, a0, a1, a2, a3); GSTEP(dA3, qA3, a0, a1, a2, a3);
            eA += 8;
        }
        while (eB < e1B) {
            uint2 dB0 = sorted[eB + 0 + hsel];
            uint2 dB1 = sorted[eB + 2 + hsel];
            uint2 dB2 = sorted[eB + 4 + hsel];
            uint2 dB3 = sorted[eB + 6 + hsel];
            uint2 qB0 = h2[dB0.x * 32u + hl];
            uint2 qB1 = h2[dB1.x * 32u + hl];
            uint2 qB2 = h2[dB2.x * 32u + hl];
            uint2 qB3 = h2[dB3.x * 32u + hl];
            GSTEP(dB0, qB0, b0, b1, b2, b3); GSTEP(dB1, qB1, b0, b1, b2, b3);
            GSTEP(dB2, qB2, b0, b1, b2, b3); GSTEP(dB3, qB3, b0, b1, b2, b3);
            eB += 8;
        }
        // fold the two halves: each feature group summed across lane^32
        a0 += __shfl_xor(a0, 32, 64); a1 += __shfl_xor(a1, 32, 64);
        a2 += __shfl_xor(a2, 32, 64); a3 += __shfl_xor(a3, 32, 64);
        b0 += __shfl_xor(b0, 32, 64); b1 += __shfl_xor(b1, 32, 64);
        b2 += __shfl_xor(b2, 32, 64); b3 += __shfl_xor(b3, 32, 64);
        if (lane < 32) {
            int cA = (rlA & 7) << 2, cB = (rlB & 7) << 2;
            uint2 wA, wB;
            wA.x = f2bf(a0) | (f2bf(a1) << 16); wA.y = f2bf(a2) | (f2bf(a3) << 16);
            wB.x = f2bf(b0) | (f2bf(b1) << 16); wB.y = f2bf(b2) | (f2bf(b3) << 16);
            *(uint2*)&lp[rlA * 64 + ((2 * hl) ^ cA)] = wA;   // (2hl)^c even -> 8B aligned
            *(uint2*)&lp[rlB * 64 + ((2 * hl) ^ cB)] = wB;
        }
    }
    __syncthreads();

    // phase E: wave wv -> rows (wv&1)*16..+15, cols (wv>>1)*64..+63
    int m = lane & 15, q = lane >> 4;
    int rl0 = (wv & 1) << 4;
    int colb = (wv >> 1) << 6;
    int rlm = rl0 + m;
    short8_t a[4];
#pragma unroll
    for (int tt = 0; tt < 4; ++tt) {
        int w0 = (q * 4 + tt * 16) ^ ((rlm & 7) << 2);
        a[tt] = *(const short8_t*)&lp[rlm * 64 + w0];
    }
#pragma unroll
    for (int ct = 0; ct < 4; ++ct) {
        int col0 = colb + ct * 16;
        const uint16_t* brow = WT + (size_t)(col0 + m) * FDIM + q * 8;
        f32x4_t acc = {0.f, 0.f, 0.f, 0.f};
#pragma unroll
        for (int tt = 0; tt < 4; ++tt) {
            short8_t bb = *(const short8_t*)(brow + tt * 32);
            acc = __builtin_amdgcn_mfma_f32_16x16x32_bf16(a[tt], bb, acc, 0, 0, 0);
        }
        float bs = bias[col0 + m];
#pragma unroll
        for (int r = 0; r < 4; ++r)
            out[(size_t)(r0 + rl0 + q * 4 + r) * FDIM + col0 + m] = acc[r] + bs;
    }
}

extern "C" void kernel_launch(void* const* d_in, const int* in_sizes, int n_in,
                              void* d_out, int out_size, void* d_ws, size_t ws_size,
                              hipStream_t stream) {
    const float* x     = (const float*)d_in[0];
    const int*   erows = (const int*)d_in[1];
    const int*   ecols = (const int*)d_in[2];
    const float* evals = (const float*)d_in[3];
    const int*   erels = (const int*)d_in[4];
    const float* relc  = (const float*)d_in[5];
    const float* ck    = (const float*)d_in[6];
    const float* W     = (const float*)d_in[7];
    const float* bias  = (const float*)d_in[8];
    const float* gamma = (const float*)d_in[9];
    const float* beta  = (const float*)d_in[10];
    const float* mean  = (const float*)d_in[11];
    const float* var   = (const float*)d_in[12];
    float* out = (float*)d_out;

    char* wp = (char*)d_ws;
    auto alloc = [&](size_t bytes) {
        char* p = wp;
        wp += (bytes + 255) & ~(size_t)255;
        return (void*)p;
    };
    uint16_t* h      = (uint16_t*)alloc((size_t)N_PAD * FDIM * 2);       // 25.6 MB
    uint2* staging   = (uint2*)alloc((size_t)NBUCK * SCAP * 8);          // 19.2 MB
    int* gcur        = (int*)alloc((size_t)NBUCK * 4);
    uint16_t* WT     = (uint16_t*)alloc(FDIM * FDIM * 2);
    if ((size_t)(wp - (char*)d_ws) > ws_size) return;

    hipMemsetAsync(gcur, 0, (size_t)NBUCK * 4, stream);
    pre_kernel<<<NBLK + 1 + HBLK, 512, 0, stream>>>(
        x, erows, ecols, evals, erels, relc, gamma, beta, mean, var, W,
        (uint2*)h, WT, gcur, staging);
    sg_kernel<<<NBUCK, 256, 0, stream>>>((const uint32_t*)h, gcur, staging, ck,
                                         WT, bias, out);
}